// Round 20
// baseline (175.167 us; speedup 1.0000x reference)
//
#include <hip/hip_runtime.h>
#include <math.h>

typedef __attribute__((ext_vector_type(8))) short bf16x8;
typedef __attribute__((ext_vector_type(4))) float f32x4;

#define Dd 256
#define Hh 1024
#define Kk 128
#define MROWS 16
#define LDI 280
#define LDH 1048
#define LDY 268

static __device__ __forceinline__ unsigned short f2bf(float f) {
    unsigned u = __builtin_bit_cast(unsigned, f);
    unsigned r = (u + 0x7fffu + ((u >> 16) & 1u)) >> 16;   // RNE
    return (unsigned short)r;
}

static __device__ __forceinline__ float fast_tanh(float x) {
    const float e = __expf(2.0f * x);
    return 1.0f - 2.0f / (e + 1.0f);
}

// ---- merged LDS-transpose pack (UNCHANGED layouts — verified passing) ------
__global__ __launch_bounds__(256) void pack_weights(
    const float* __restrict__ W1, const float* __restrict__ W2,
    unsigned short* __restrict__ W1P, unsigned short* __restrict__ W2P)
{
    __shared__ unsigned short tile[128 * 33];
    const int tid = threadIdx.x;
    const int b = blockIdx.x;
    if (b < 128) {
        const int kst = b & 7;
        const int wpp = b >> 3;
        const int n0 = wpp * 64;
        const int k0 = kst * 32;
#pragma unroll
        for (int it = 0; it < 8; ++it) {
            const int i = it * 256 + tid;
            const int kk = i >> 6, nn = i & 63;
            tile[kk * 65 + nn] = f2bf(W1[(size_t)(k0 + kk) * Hh + n0 + nn]);
        }
        __syncthreads();
#pragma unroll
        for (int it = 0; it < 8; ++it) {
            const int i = it * 256 + tid;
            const int ct = i >> 9;
            const int lane = (i >> 3) & 63;
            const int j = i & 7;
            const int kk = (lane >> 4) * 8 + j;
            const int nn = ct * 16 + (lane & 15);
            W1P[(size_t)b * 2048 + i] = tile[kk * 65 + nn];
        }
    } else {
        const int u = b - 128;
        const int kseg = u & 7;
        const int w = u >> 3;
        const int n0 = w * 32;
        const int k0 = kseg * 128;
#pragma unroll
        for (int it = 0; it < 16; ++it) {
            const int i = it * 256 + tid;
            const int kk = i >> 5, nn = i & 31;
            tile[kk * 33 + nn] = f2bf(W2[(size_t)(k0 + kk) * Dd + n0 + nn]);
        }
        __syncthreads();
#pragma unroll
        for (int it = 0; it < 16; ++it) {
            const int i = it * 256 + tid;
            const int kst = i >> 10;
            const int ct = (i >> 9) & 1;
            const int lane = (i >> 3) & 63;
            const int j = i & 7;
            const int kk = kst * 32 + (lane >> 4) * 8 + j;
            const int nn = ct * 16 + (lane & 15);
            W2P[(size_t)u * 4096 + i] = tile[kk * 33 + nn];
        }
    }
}

// R19 RK3 kernel (passing, 44.7 µs, absmax 0.0625) + 96 KB LDS weight cache:
// W1P kst=0/ct0..1 (32 KB) and W2P kseg=0 (64 KB) copied to LDS once, read
// from LDS every eval (first fragments after each barrier -> immediate MFMAs
// while the L2 stream ramps). Values and per-accumulator MFMA chain order
// identical -> bit-exact (absmax must stay 0.0625). Tests the per-CU
// L2-ingress-floor theory: -9.4% L2 bytes/eval.
__global__ __launch_bounds__(1024, 4) void ode_fused(
    const float* __restrict__ x,
    const unsigned short* __restrict__ W1P,
    const float* __restrict__ b1,
    const unsigned short* __restrict__ W2P,
    const float* __restrict__ b2,
    const int* __restrict__ indices,
    float* __restrict__ out)
{
    __shared__ __align__(16) unsigned short in_bf[MROWS * LDI];   // 8.75 KB
    __shared__ __align__(16) unsigned short hid[MROWS * LDH];     // 32.75 KB
    __shared__ __align__(16) unsigned short wc1[16384];           // 32 KB
    __shared__ __align__(16) unsigned short wc2[32768];           // 64 KB
    __shared__ float b1s[Hh];
    __shared__ float b2s[Dd];

    const int tid  = threadIdx.x;
    const int lane = tid & 63;
    const int w    = tid >> 6;      // wave 0..15
    const int quad = lane >> 4;
    const int l16  = lane & 15;
    const int row0 = blockIdx.x * MROWS;

    for (int i = tid; i < Hh; i += 1024) b1s[i] = b1[i];
    for (int i = tid; i < Dd; i += 1024) b2s[i] = b2[i];

    // stage weight cache (flat copies, vectorized 8-short chunks)
    for (int i = tid * 8; i < 16384; i += 8192) {
        const int ww = i >> 10, rem = i & 1023;
        *(uint4*)&wc1[i] = *(const uint4*)&W1P[(size_t)ww * 16384 + rem];
    }
    for (int i = tid * 8; i < 32768; i += 8192) {
        const int pr = i >> 12, rem = i & 4095;
        *(uint4*)&wc2[i] = *(const uint4*)&W2P[(size_t)pr * 32768 + rem];
    }

    float yv[4], av[4], k1v[4];
    const int scol = w * 16 + quad * 4;
    {
        const float4 v = *(const float4*)&x[(size_t)(row0 + l16) * Dd + scol];
        yv[0] = v.x; yv[1] = v.y; yv[2] = v.z; yv[3] = v.w;
        const unsigned u0 = (unsigned)f2bf(v.x) | ((unsigned)f2bf(v.y) << 16);
        const unsigned u1 = (unsigned)f2bf(v.z) | ((unsigned)f2bf(v.w) << 16);
        *(uint2*)&in_bf[l16 * LDI + scol] = make_uint2(u0, u1);
    }
    __syncthreads();

    const float h  = 1.0f;
    const float h6 = h / 6.0f, h2 = h * 0.5f, h46 = 4.0f * h / 6.0f;

    const unsigned short* w1w = W1P + (size_t)w * 16384 + (size_t)lane * 8;
    const unsigned short* w2w = W2P + (size_t)(w >> 1) * 32768
                                    + (size_t)(w & 1) * 512 + (size_t)lane * 8;
    const unsigned short* wc1w = wc1 + w * 1024 + lane * 8;
    const unsigned short* wc2w = wc2 + (w >> 1) * 4096 + (w & 1) * 512 + lane * 8;

#pragma unroll 1
    for (int e = 0; e < 3; ++e) {
        // ---- GEMM1: hid cols [w*64,+64) = tanh(in_bf @ W1 + b1)
        f32x4 acc[4] = {};
        {   // kst = 0: ct 0,1 from LDS cache; ct 2,3 from L2
            const bf16x8 bf = *(const bf16x8*)&in_bf[l16 * LDI + quad * 8];
            const bf16x8 a0 = *(const bf16x8*)(wc1w);
            const bf16x8 a1 = *(const bf16x8*)(wc1w + 512);
            const bf16x8 a2 = *(const bf16x8*)(w1w + (size_t)2 * 512);
            const bf16x8 a3 = *(const bf16x8*)(w1w + (size_t)3 * 512);
            acc[0] = __builtin_amdgcn_mfma_f32_16x16x32_bf16(a0, bf, acc[0], 0, 0, 0);
            acc[1] = __builtin_amdgcn_mfma_f32_16x16x32_bf16(a1, bf, acc[1], 0, 0, 0);
            acc[2] = __builtin_amdgcn_mfma_f32_16x16x32_bf16(a2, bf, acc[2], 0, 0, 0);
            acc[3] = __builtin_amdgcn_mfma_f32_16x16x32_bf16(a3, bf, acc[3], 0, 0, 0);
        }
#pragma unroll 2
        for (int kst = 1; kst < 8; ++kst) {
            const bf16x8 bf = *(const bf16x8*)&in_bf[l16 * LDI + kst * 32 + quad * 8];
            bf16x8 aw[4];
#pragma unroll
            for (int ct = 0; ct < 4; ++ct)
                aw[ct] = *(const bf16x8*)(w1w + (size_t)(kst * 4 + ct) * 512);
#pragma unroll
            for (int ct = 0; ct < 4; ++ct)
                acc[ct] = __builtin_amdgcn_mfma_f32_16x16x32_bf16(
                    aw[ct], bf, acc[ct], 0, 0, 0);
        }
#pragma unroll
        for (int ct = 0; ct < 4; ++ct) {
            const int col = w * 64 + ct * 16 + quad * 4;
            const float4 bb = *(const float4*)&b1s[col];
            const unsigned short h0 = f2bf(fast_tanh(acc[ct][0] + bb.x));
            const unsigned short h1 = f2bf(fast_tanh(acc[ct][1] + bb.y));
            const unsigned short h2b = f2bf(fast_tanh(acc[ct][2] + bb.z));
            const unsigned short h3b = f2bf(fast_tanh(acc[ct][3] + bb.w));
            const unsigned u0 = (unsigned)h0 | ((unsigned)h1 << 16);
            const unsigned u1 = (unsigned)h2b | ((unsigned)h3b << 16);
            *(uint2*)&hid[l16 * LDH + col] = make_uint2(u0, u1);
        }
        __syncthreads();

        // ---- GEMM2: F for state cols [w*16,+16) = hid @ W2 + b2
        f32x4 acc2 = {};
#pragma unroll
        for (int kst = 0; kst < 4; ++kst) {   // kseg = 0 from LDS cache
            const bf16x8 bh = *(const bf16x8*)&hid[l16 * LDH + kst * 32 + quad * 8];
            const bf16x8 aw = *(const bf16x8*)(wc2w + (size_t)kst * 1024);
            acc2 = __builtin_amdgcn_mfma_f32_16x16x32_bf16(aw, bh, acc2, 0, 0, 0);
        }
#pragma unroll 2
        for (int kseg = 1; kseg < 8; ++kseg) {
#pragma unroll
            for (int kst = 0; kst < 4; ++kst) {
                const bf16x8 bh = *(const bf16x8*)&hid[l16 * LDH + kseg * 128 + kst * 32 + quad * 8];
                const bf16x8 aw = *(const bf16x8*)(w2w + (size_t)(kseg * 4 + kst) * 1024);
                acc2 = __builtin_amdgcn_mfma_f32_16x16x32_bf16(aw, bh, acc2, 0, 0, 0);
            }
        }
        // ---- RK3 stage update (registers)
        {
            const float4 bb = *(const float4*)&b2s[scol];
            float tmp[4];
#pragma unroll
            for (int r = 0; r < 4; ++r) {
                const float F = acc2[r] + ((const float*)&bb)[r];
                if (e == 0) {
                    k1v[r] = F;
                    av[r] = yv[r] + h6 * F;
                    tmp[r] = yv[r] + h2 * F;
                } else if (e == 1) {
                    av[r] += h46 * F;
                    tmp[r] = yv[r] + h * (2.0f * F - k1v[r]);
                } else {
                    yv[r] = av[r] + h6 * F;
                    tmp[r] = yv[r];
                }
            }
            const unsigned u0 = (unsigned)f2bf(tmp[0]) | ((unsigned)f2bf(tmp[1]) << 16);
            const unsigned u1 = (unsigned)f2bf(tmp[2]) | ((unsigned)f2bf(tmp[3]) << 16);
            *(uint2*)&in_bf[l16 * LDI + scol] = make_uint2(u0, u1);
        }
        __syncthreads();
    }

    // final state -> LDS (reuse hid as fp32) -> gather
    float* yf = (float*)hid;
    {
        float4 v;
        v.x = yv[0]; v.y = yv[1]; v.z = yv[2]; v.w = yv[3];
        *(float4*)&yf[l16 * LDY + scol] = v;
    }
    __syncthreads();

    for (int i = tid; i < MROWS * Kk; i += 1024) {
        const int row = i >> 7;
        const int kc  = i & (Kk - 1);
        const int gi  = (row0 + row) * Kk + kc;
        out[gi] = yf[row * LDY + indices[gi]];
    }
}

extern "C" void kernel_launch(void* const* d_in, const int* in_sizes, int n_in,
                              void* d_out, int out_size, void* d_ws, size_t ws_size,
                              hipStream_t stream)
{
    const float* x  = (const float*)d_in[0];
    const float* W1 = (const float*)d_in[1];
    const float* b1 = (const float*)d_in[2];
    const float* W2 = (const float*)d_in[3];
    const float* b2 = (const float*)d_in[4];
    const int* indices = (const int*)d_in[5];
    float* out = (float*)d_out;

    const int H = in_sizes[2];        // 1024
    const int D = in_sizes[4];        // 256
    const int B = in_sizes[0] / D;    // 4096

    unsigned short* W1P = (unsigned short*)d_ws;                 // 512 KB
    unsigned short* W2P = W1P + (size_t)H * D;                   // 512 KB

    pack_weights<<<192, 256, 0, stream>>>(W1, W2, W1P, W2P);

    ode_fused<<<B / MROWS, 1024, 0, stream>>>(x, W1P, b1, W2P, b2, indices, out);
}

// Round 21
// 104.349 us; speedup vs baseline: 1.6787x; 1.6787x over previous
//
#include <hip/hip_runtime.h>
#include <math.h>

typedef __attribute__((ext_vector_type(8))) short bf16x8;
typedef __attribute__((ext_vector_type(4))) float f32x4;

#define Dd 256
#define Hh 1024
#define Kk 128
#define MROWS 16
#define LDI 280
#define LDH 1048
#define LDY 268

static __device__ __forceinline__ unsigned short f2bf(float f) {
    unsigned u = __builtin_bit_cast(unsigned, f);
    unsigned r = (u + 0x7fffu + ((u >> 16) & 1u)) >> 16;   // RNE
    return (unsigned short)r;
}

static __device__ __forceinline__ float fast_tanh(float x) {
    const float e = __expf(2.0f * x);
    return 1.0f - 2.0f / (e + 1.0f);
}

// ---- merged LDS-transpose pack (verified passing layouts) ------------------
__global__ __launch_bounds__(256) void pack_weights(
    const float* __restrict__ W1, const float* __restrict__ W2,
    unsigned short* __restrict__ W1P, unsigned short* __restrict__ W2P)
{
    __shared__ unsigned short tile[128 * 33];
    const int tid = threadIdx.x;
    const int b = blockIdx.x;
    if (b < 128) {
        const int kst = b & 7;
        const int wpp = b >> 3;
        const int n0 = wpp * 64;
        const int k0 = kst * 32;
#pragma unroll
        for (int it = 0; it < 8; ++it) {
            const int i = it * 256 + tid;
            const int kk = i >> 6, nn = i & 63;
            tile[kk * 65 + nn] = f2bf(W1[(size_t)(k0 + kk) * Hh + n0 + nn]);
        }
        __syncthreads();
#pragma unroll
        for (int it = 0; it < 8; ++it) {
            const int i = it * 256 + tid;
            const int ct = i >> 9;
            const int lane = (i >> 3) & 63;
            const int j = i & 7;
            const int kk = (lane >> 4) * 8 + j;
            const int nn = ct * 16 + (lane & 15);
            W1P[(size_t)b * 2048 + i] = tile[kk * 65 + nn];
        }
    } else {
        const int u = b - 128;
        const int kseg = u & 7;
        const int w = u >> 3;
        const int n0 = w * 32;
        const int k0 = kseg * 128;
#pragma unroll
        for (int it = 0; it < 16; ++it) {
            const int i = it * 256 + tid;
            const int kk = i >> 5, nn = i & 31;
            tile[kk * 33 + nn] = f2bf(W2[(size_t)(k0 + kk) * Dd + n0 + nn]);
        }
        __syncthreads();
#pragma unroll
        for (int it = 0; it < 16; ++it) {
            const int i = it * 256 + tid;
            const int kst = i >> 10;
            const int ct = (i >> 9) & 1;
            const int lane = (i >> 3) & 63;
            const int j = i & 7;
            const int kk = kst * 32 + (lane >> 4) * 8 + j;
            const int nn = ct * 16 + (lane & 15);
            W2P[(size_t)u * 4096 + i] = tile[kk * 33 + nn];
        }
    }
}

// FINAL (= R19, best passing: kernel 44.7 µs, absmax 0.0625, VGPR 40, no
// spill). RK3 Kutta, h=1, 3 MLP evals. One block = 16 waves = 1024 thr,
// 16 rows/block, grid 256. Fragment-major packed weights streamed from L2
// (~1 MB/CU/eval at ~30 B/cyc — ~92% of the per-CU ingress floor).
// Lessons encoded: no live set > ~55 regs (64-tier spill: R4-R7/R15/R17/R20);
// no arithmetic-path restructure (bf16 rounding flips: R12).
__global__ __launch_bounds__(1024, 4) void ode_fused(
    const float* __restrict__ x,
    const unsigned short* __restrict__ W1P,
    const float* __restrict__ b1,
    const unsigned short* __restrict__ W2P,
    const float* __restrict__ b2,
    const int* __restrict__ indices,
    float* __restrict__ out)
{
    __shared__ __align__(16) unsigned short in_bf[MROWS * LDI];
    __shared__ __align__(16) unsigned short hid[MROWS * LDH];
    __shared__ float b1s[Hh];
    __shared__ float b2s[Dd];

    const int tid  = threadIdx.x;
    const int lane = tid & 63;
    const int w    = tid >> 6;      // wave 0..15
    const int quad = lane >> 4;
    const int l16  = lane & 15;
    const int row0 = blockIdx.x * MROWS;

    for (int i = tid; i < Hh; i += 1024) b1s[i] = b1[i];
    for (int i = tid; i < Dd; i += 1024) b2s[i] = b2[i];

    float yv[4], av[4], k1v[4];
    const int scol = w * 16 + quad * 4;
    {
        const float4 v = *(const float4*)&x[(size_t)(row0 + l16) * Dd + scol];
        yv[0] = v.x; yv[1] = v.y; yv[2] = v.z; yv[3] = v.w;
        const unsigned u0 = (unsigned)f2bf(v.x) | ((unsigned)f2bf(v.y) << 16);
        const unsigned u1 = (unsigned)f2bf(v.z) | ((unsigned)f2bf(v.w) << 16);
        *(uint2*)&in_bf[l16 * LDI + scol] = make_uint2(u0, u1);
    }
    __syncthreads();

    const float h  = 1.0f;
    const float h6 = h / 6.0f, h2 = h * 0.5f, h46 = 4.0f * h / 6.0f;

    const unsigned short* w1w = W1P + (size_t)w * 16384 + (size_t)lane * 8;
    const unsigned short* w2w = W2P + (size_t)(w >> 1) * 32768
                                    + (size_t)(w & 1) * 512 + (size_t)lane * 8;

#pragma unroll 1
    for (int e = 0; e < 3; ++e) {
        // ---- GEMM1: hid cols [w*64,+64) = tanh(in_bf @ W1 + b1)
        f32x4 acc[4] = {};
#pragma unroll 2
        for (int kst = 0; kst < 8; ++kst) {
            const bf16x8 bf = *(const bf16x8*)&in_bf[l16 * LDI + kst * 32 + quad * 8];
            bf16x8 aw[4];
#pragma unroll
            for (int ct = 0; ct < 4; ++ct)
                aw[ct] = *(const bf16x8*)(w1w + (size_t)(kst * 4 + ct) * 512);
#pragma unroll
            for (int ct = 0; ct < 4; ++ct)
                acc[ct] = __builtin_amdgcn_mfma_f32_16x16x32_bf16(
                    aw[ct], bf, acc[ct], 0, 0, 0);
        }
#pragma unroll
        for (int ct = 0; ct < 4; ++ct) {
            const int col = w * 64 + ct * 16 + quad * 4;
            const float4 bb = *(const float4*)&b1s[col];
            const unsigned short h0 = f2bf(fast_tanh(acc[ct][0] + bb.x));
            const unsigned short h1 = f2bf(fast_tanh(acc[ct][1] + bb.y));
            const unsigned short h2b = f2bf(fast_tanh(acc[ct][2] + bb.z));
            const unsigned short h3b = f2bf(fast_tanh(acc[ct][3] + bb.w));
            const unsigned u0 = (unsigned)h0 | ((unsigned)h1 << 16);
            const unsigned u1 = (unsigned)h2b | ((unsigned)h3b << 16);
            *(uint2*)&hid[l16 * LDH + col] = make_uint2(u0, u1);
        }
        __syncthreads();

        // ---- GEMM2: F for state cols [w*16,+16) = hid @ W2 + b2
        f32x4 acc2 = {};
#pragma unroll 2
        for (int kseg = 0; kseg < 8; ++kseg) {
#pragma unroll
            for (int kst = 0; kst < 4; ++kst) {
                const bf16x8 bh = *(const bf16x8*)&hid[l16 * LDH + kseg * 128 + kst * 32 + quad * 8];
                const bf16x8 aw = *(const bf16x8*)(w2w + (size_t)(kseg * 4 + kst) * 1024);
                acc2 = __builtin_amdgcn_mfma_f32_16x16x32_bf16(aw, bh, acc2, 0, 0, 0);
            }
        }
        // ---- RK3 stage update (registers)
        {
            const float4 bb = *(const float4*)&b2s[scol];
            float tmp[4];
#pragma unroll
            for (int r = 0; r < 4; ++r) {
                const float F = acc2[r] + ((const float*)&bb)[r];
                if (e == 0) {
                    k1v[r] = F;
                    av[r] = yv[r] + h6 * F;
                    tmp[r] = yv[r] + h2 * F;
                } else if (e == 1) {
                    av[r] += h46 * F;
                    tmp[r] = yv[r] + h * (2.0f * F - k1v[r]);
                } else {
                    yv[r] = av[r] + h6 * F;
                    tmp[r] = yv[r];
                }
            }
            const unsigned u0 = (unsigned)f2bf(tmp[0]) | ((unsigned)f2bf(tmp[1]) << 16);
            const unsigned u1 = (unsigned)f2bf(tmp[2]) | ((unsigned)f2bf(tmp[3]) << 16);
            *(uint2*)&in_bf[l16 * LDI + scol] = make_uint2(u0, u1);
        }
        __syncthreads();
    }

    // final state -> LDS (reuse hid as fp32) -> gather
    float* yf = (float*)hid;
    {
        float4 v;
        v.x = yv[0]; v.y = yv[1]; v.z = yv[2]; v.w = yv[3];
        *(float4*)&yf[l16 * LDY + scol] = v;
    }
    __syncthreads();

    for (int i = tid; i < MROWS * Kk; i += 1024) {
        const int row = i >> 7;
        const int kc  = i & (Kk - 1);
        const int gi  = (row0 + row) * Kk + kc;
        out[gi] = yf[row * LDY + indices[gi]];
    }
}

extern "C" void kernel_launch(void* const* d_in, const int* in_sizes, int n_in,
                              void* d_out, int out_size, void* d_ws, size_t ws_size,
                              hipStream_t stream)
{
    const float* x  = (const float*)d_in[0];
    const float* W1 = (const float*)d_in[1];
    const float* b1 = (const float*)d_in[2];
    const float* W2 = (const float*)d_in[3];
    const float* b2 = (const float*)d_in[4];
    const int* indices = (const int*)d_in[5];
    float* out = (float*)d_out;

    const int H = in_sizes[2];        // 1024
    const int D = in_sizes[4];        // 256
    const int B = in_sizes[0] / D;    // 4096

    unsigned short* W1P = (unsigned short*)d_ws;                 // 512 KB
    unsigned short* W2P = W1P + (size_t)H * D;                   // 512 KB

    pack_weights<<<192, 256, 0, stream>>>(W1, W2, W1P, W2P);

    ode_fused<<<B / MROWS, 1024, 0, stream>>>(x, W1P, b1, W2P, b2, indices, out);
}